// Round 15
// baseline (1272.228 us; speedup 1.0000x reference)
//
#include <hip/hip_runtime.h>

// ---------------------------------------------------------------------------
// Deformation MLP, MI355X (gfx950).  Round 15: 2-product trunk.
// Trunk layers use (a_hi + a_lo) * w_hi — activations exact, error = weight
// quantization only (Δs_tail ~ 1.6e-4). Compensated by enlarged sensitivity
// repair: th^2 < 1e-4*(|x|^2+|t|^2) -> exact fp32 recompute (~10^2-10^3 pts).
// Out-layer keeps 3 products (cheap, feeds s directly).
// Per-tile MFMA 252 -> 176; chain LDS reads halve; W0/1/2 lo tables gone.
// Structure = r14 (serial per-ft chains, dual-acc, all-hi-weights in LDS,
// WO streamed from L2, literal-f32 Rodrigues) — proven spill-free.
// ---------------------------------------------------------------------------

typedef __fp16   fp16x2 __attribute__((ext_vector_type(2)));
typedef _Float16 f16x8  __attribute__((ext_vector_type(8)));
typedef float    f32x4  __attribute__((ext_vector_type(4)));
typedef float    f32x16 __attribute__((ext_vector_type(16)));
typedef unsigned u32x4  __attribute__((ext_vector_type(4)));

#define PI_F 3.14159265358979323846f
constexpr int   BATCH = 2048;
constexpr int   NPTS  = BATCH * 128;
constexpr float IPE_VAR = 1e-4f;
constexpr float KAPPA2_X2 = 1e-4f;   // repair if th^2 < this*(xx+tt)

// ---- ws layout (bytes) ----
constexpr int WSO_V    = 0;          // 1,048,576
constexpr int WSO_S    = 1048576;    // 6,291,456
constexpr int WSO_PART = 7340032;    // 24,576
constexpr int WSO_TAB  = 7364608;    // hi tables copied to LDS:
constexpr int TB_W0H = 0;            // 128x48  hi : 12288
constexpr int TB_W1H = 12288;        // 128x128 hi : 32768
constexpr int TB_W2H = 45056;        // 128x128 hi : 32768
constexpr int TB_SZ  = 77824;        // 76 KB tables
constexpr int WSO_WOH = WSO_TAB + TB_SZ;          // 8192 (streamed from L2)
constexpr int WSO_WOL = WSO_TAB + TB_SZ + 8192;   // 8192 (streamed from L2)

// ---- extra LDS past the tables ----
constexpr int OFF_B1   = TB_SZ;            // 512
constexpr int OFF_B2   = TB_SZ + 512;      // 512
constexpr int OFF_VR   = TB_SZ + 1024;     // 8 rows x 128 f32 = 4096
constexpr int SMEM_TOT = TB_SZ + 1024 + 4096;   // 82,944 B

__device__ __forceinline__ float read_ds(const int* p) {
    int iv = p[0];
    if (iv >= 0 && iv <= 64) return (float)iv;
    return ((const float*)p)[0];
}

// exact hi/lo fp16 split of a float pair: hi = pkrtz(a,b); lo absorbs residual
__device__ __forceinline__ void split2(float a, float b, unsigned& hi, unsigned& lo) {
    fp16x2 h = __builtin_amdgcn_cvt_pkrtz(a, b);
    fp16x2 l = __builtin_amdgcn_cvt_pkrtz(a - (float)h[0], b - (float)h[1]);
    hi = __builtin_bit_cast(unsigned, h);
    lo = __builtin_bit_cast(unsigned, l);
}

// v_permlane32_swap_b32: a' = {a[0:31], b[0:31]}, b' = {a[32:63], b[32:63]}
__device__ __forceinline__ void permswap(unsigned& a, unsigned& b) {
    asm("v_permlane32_swap_b32 %0, %1" : "+v"(a), "+v"(b));
}

// ===========================================================================
// K1: per-batch prep. grid 256 x 128 threads, 8 batches per block.
// ===========================================================================
__launch_bounds__(128)
__global__ void prep_kernel(const float* __restrict__ dc, const float* __restrict__ wproj,
                            const float* __restrict__ bproj, const float* __restrict__ w0,
                            const float* __restrict__ b0, float* __restrict__ vws) {
    __shared__ float dcn[8][128];
    __shared__ float dcp[8][128];
    __shared__ float red[2];
    const int tid = threadIdx.x;
    const int bb  = blockIdx.x * 8;

    for (int bi = 0; bi < 8; ++bi) {
        float val = dc[(bb + bi) * 128 + tid];
        float sq  = val * val;
        for (int off = 32; off; off >>= 1) sq += __shfl_down(sq, off);
        if ((tid & 63) == 0) red[tid >> 6] = sq;
        __syncthreads();
        float nrm = sqrtf(red[0] + red[1]);
        dcn[bi][tid] = val / fmaxf(nrm, 1e-12f);
        __syncthreads();
    }
    float acc[8];
#pragma unroll
    for (int bi = 0; bi < 8; ++bi) acc[bi] = bproj[tid];
    for (int c = 0; c < 128; ++c) {
        float w = wproj[c * 128 + tid];
#pragma unroll
        for (int bi = 0; bi < 8; ++bi) acc[bi] += dcn[bi][c] * w;
    }
#pragma unroll
    for (int bi = 0; bi < 8; ++bi) dcp[bi][tid] = acc[bi];
    __syncthreads();
#pragma unroll
    for (int bi = 0; bi < 8; ++bi) acc[bi] = b0[tid];
    for (int c = 0; c < 128; ++c) {
        float w = w0[(96 + c) * 128 + tid];
#pragma unroll
        for (int bi = 0; bi < 8; ++bi) acc[bi] += dcp[bi][c] * w;
    }
#pragma unroll
    for (int bi = 0; bi < 8; ++bi) vws[(bb + bi) * 128 + tid] = acc[bi];
}

// ===========================================================================
// K1b: build fragment-linear (32x32x16 form) fp16 weight tables in ws.
// W0/W1/W2: hi only. WO: hi + lo.
// ===========================================================================
__launch_bounds__(256)
__global__ void lofill_kernel(const float* __restrict__ w0, const float* __restrict__ w1,
                              const float* __restrict__ w2, const float* __restrict__ wout,
                              char* __restrict__ ws) {
    int i = blockIdx.x * 256 + threadIdx.x;
    if (i >= 5376) return;
    float src[8];
    int dstH, dstL = -1;
    if (i < 768) {                          // W0: 128 n x 6 kb (K=48, G=3)
        int n = i & 127, kb = i >> 7;
#pragma unroll
        for (int j = 0; j < 8; ++j) src[j] = w0[(kb * 8 + j) * 128 + n];
        int off = ((n >> 5) * 3 + (kb >> 1)) * 1024 + (((n & 31) | ((kb & 1) << 5)) << 4);
        dstH = WSO_TAB + TB_W0H + off;
    } else if (i < 768 + 2048) {            // W1: 128 x 16 kb (G=8)
        int t = i - 768; int n = t & 127, kb = t >> 7;
#pragma unroll
        for (int j = 0; j < 8; ++j) src[j] = w1[(kb * 8 + j) * 128 + n];
        int off = ((n >> 5) * 8 + (kb >> 1)) * 1024 + (((n & 31) | ((kb & 1) << 5)) << 4);
        dstH = WSO_TAB + TB_W1H + off;
    } else if (i < 768 + 4096) {            // W2
        int t = i - 768 - 2048; int n = t & 127, kb = t >> 7;
#pragma unroll
        for (int j = 0; j < 8; ++j) src[j] = w2[(kb * 8 + j) * 128 + n];
        int off = ((n >> 5) * 8 + (kb >> 1)) * 1024 + (((n & 31) | ((kb & 1) << 5)) << 4);
        dstH = WSO_TAB + TB_W2H + off;
    } else {                                // WO: 32 idx (6 real) x 16 kb (G=8)
        int t = i - 768 - 4096; int idx = t & 31, kb = t >> 5;
#pragma unroll
        for (int j = 0; j < 8; ++j) {
            int k = kb * 8 + j;
            src[j] = (idx < 6) ? wout[k * 6 + idx] : 0.f;
        }
        int off = (kb >> 1) * 1024 + (((idx & 31) | ((kb & 1) << 5)) << 4);
        dstH = WSO_WOH + off;  dstL = WSO_WOL + off;
    }
    f16x8 vh, vl;
#pragma unroll
    for (int j = 0; j < 8; ++j) {
        _Float16 h = (_Float16)src[j];
        vh[j] = h;
        vl[j] = (_Float16)(src[j] - (float)h);
    }
    *(f16x8*)(ws + dstH) = vh;
    if (dstL >= 0) *(f16x8*)(ws + dstL) = vl;
}

// ===========================================================================
// K2: fused MLP, barrier-free, per-ft serial chains + dual-acc ILP.
// 2-product trunk (hi weights only). grid 256 x 512 (8 waves).
// ===========================================================================
__device__ __forceinline__ void transition_ft(const f32x16& acc, int ft,
                                              f16x8 (&Bh)[8], f16x8 (&Bl)[8]) {
    unsigned hp[8], lp[8];
#pragma unroll
    for (int r2 = 0; r2 < 8; ++r2) {
        float f0 = fmaxf(acc[2 * r2],     0.f);
        float f1 = fmaxf(acc[2 * r2 + 1], 0.f);
        split2(f0, f1, hp[r2], lp[r2]);
    }
#pragma unroll
    for (int gg = 0; gg < 2; ++gg) {
        int g = 2 * ft + gg, P = 4 * gg;
        unsigned a = hp[P], b = hp[P + 1], c = hp[P + 2], d = hp[P + 3];
        permswap(a, c); permswap(b, d);
        Bh[g] = __builtin_bit_cast(f16x8, (u32x4){a, b, c, d});
        a = lp[P]; b = lp[P + 1]; c = lp[P + 2]; d = lp[P + 3];
        permswap(a, c); permswap(b, d);
        Bl[g] = __builtin_bit_cast(f16x8, (u32x4){a, b, c, d});
    }
}

__global__ void __launch_bounds__(512, 2)
mlp_kernel(const float* __restrict__ x,  const float* __restrict__ b1,
           const float* __restrict__ b2, const float* __restrict__ bout,
           const int* __restrict__ dsp,  const float* __restrict__ vws,
           float* __restrict__ sws,      const char* __restrict__ ws) {
    alignas(16) __shared__ char smem[SMEM_TOT];
    const int tid  = threadIdx.x;
    const int lane = tid & 63;
    const int wv   = tid >> 6;
    const int h    = lane >> 5;      // lane half
    const int c    = lane & 31;      // point-within-32 / col

    // ---- stage hi tables + biases + vws rows -> LDS, single barrier ----
    {
        const u32x4* src = (const u32x4*)(ws + WSO_TAB);
        u32x4* dst = (u32x4*)smem;
        for (int i = tid; i < TB_SZ / 16; i += 512) dst[i] = src[i];
        if (tid < 128)      ((float*)(smem + OFF_B1))[tid]       = b1[tid];
        else if (tid < 256) ((float*)(smem + OFF_B2))[tid - 128] = b2[tid - 128];
        float* vr = (float*)(smem + OFF_VR);
        for (int i = tid; i < 1024; i += 512) vr[i] = vws[blockIdx.x * 1024 + i];
    }
    __syncthreads();

    const int laneoff = lane << 4;
    const char* W0h = smem + TB_W0H + laneoff;
    const char* W1h = smem + TB_W1H + laneoff;
    const char* W2h = smem + TB_W2H + laneoff;
    const char* WOh = ws + WSO_WOH + laneoff;   // streamed from L1/L2
    const char* WOl = ws + WSO_WOL + laneoff;

    float win[8];
    {
        float dsv = read_ds(dsp);
#pragma unroll
        for (int k2 = 0; k2 < 8; ++k2) {
            float fr = (float)(1 << k2);
            float cl = fminf(fmaxf(dsv - (float)k2, 0.f), 1.f);
            win[k2] = 0.5f * (1.f - cosf(PI_F * cl)) * expf(-0.5f * fr * fr * IPE_VAR);
        }
    }
    float bo[6];
#pragma unroll
    for (int i = 0; i < 6; ++i) bo[i] = bout[i];

    const int tbase = blockIdx.x * 32 + wv * 4;
    const int vroff = wv * 128;                 // this wave's v-row in LDS

#pragma unroll 1
    for (int it = 0; it < 4; ++it) {
        const int tile  = tbase + it;
        const int pbase = tile * 32;

        // ---- fourier embedding -> B0 frags (K=48, 3 k-slices) ----
        f16x8 B0h[3], B0l[3];
        {
            float vals[48];
            float sv[3], cv[3];
#pragma unroll
            for (int d = 0; d < 3; ++d) {
                float xv = x[(pbase + c) * 3 + d];
                sv[d] = sinf(xv); cv[d] = cosf(xv);
            }
#pragma unroll
            for (int k2 = 0; k2 < 8; ++k2) {
#pragma unroll
                for (int d = 0; d < 3; ++d) {
                    vals[6 * k2 + d]     = sv[d] * win[k2];
                    vals[6 * k2 + 3 + d] = cv[d] * win[k2];
                }
#pragma unroll
                for (int d = 0; d < 3; ++d) {
                    float ns = 2.f * sv[d] * cv[d];
                    cv[d] = 1.f - 2.f * sv[d] * sv[d];
                    sv[d] = ns;
                }
            }
#pragma unroll
            for (int g = 0; g < 3; ++g) {
                u32x4 wh_, wl_;
#pragma unroll
                for (int w = 0; w < 4; ++w) {
                    float va = h ? vals[16 * g + 8 + 2 * w]     : vals[16 * g + 2 * w];
                    float vb = h ? vals[16 * g + 8 + 2 * w + 1] : vals[16 * g + 2 * w + 1];
                    unsigned uh, ul;
                    split2(va, vb, uh, ul);
                    wh_[w] = uh; wl_[w] = ul;
                }
                B0h[g] = __builtin_bit_cast(f16x8, wh_);
                B0l[g] = __builtin_bit_cast(f16x8, wl_);
            }
        }

        // ---- L0: per-ft chain, dual acc; 2 products per g ----
        f16x8 Bh[8], Bl[8];
#pragma unroll
        for (int ft = 0; ft < 4; ++ft) {
            f32x16 aA, aB;
#pragma unroll
            for (int q4 = 0; q4 < 4; ++q4) {
                f32x4 t = *(const f32x4*)(smem + OFF_VR + (vroff + ft * 32 + 4 * h + 8 * q4) * 4);
#pragma unroll
                for (int i = 0; i < 4; ++i) { aA[4 * q4 + i] = t[i]; aB[4 * q4 + i] = 0.f; }
            }
#pragma unroll
            for (int g = 0; g < 3; ++g) {
                f32x16& t = (g & 1) ? aB : aA;
                f16x8 wh = *(const f16x8*)(W0h + (ft * 3 + g) * 1024);
                t = __builtin_amdgcn_mfma_f32_32x32x16_f16(wh, B0h[g], t, 0, 0, 0);
                t = __builtin_amdgcn_mfma_f32_32x32x16_f16(wh, B0l[g], t, 0, 0, 0);
            }
#pragma unroll
            for (int i = 0; i < 16; ++i) aA[i] += aB[i];
            transition_ft(aA, ft, Bh, Bl);
        }

        // ---- L1: per-ft chain, dual acc; B -> C; 2 products ----
        f16x8 Ch[8], Cl[8];
#pragma unroll
        for (int ft = 0; ft < 4; ++ft) {
            f32x16 aA, aB;
#pragma unroll
            for (int q4 = 0; q4 < 4; ++q4) {
                f32x4 t = *(const f32x4*)(smem + OFF_B1 + (ft * 32 + 4 * h + 8 * q4) * 4);
#pragma unroll
                for (int i = 0; i < 4; ++i) { aA[4 * q4 + i] = t[i]; aB[4 * q4 + i] = 0.f; }
            }
#pragma unroll
            for (int g = 0; g < 8; ++g) {
                f32x16& t = (g & 1) ? aB : aA;
                f16x8 wh = *(const f16x8*)(W1h + (ft * 8 + g) * 1024);
                t = __builtin_amdgcn_mfma_f32_32x32x16_f16(wh, Bh[g], t, 0, 0, 0);
                t = __builtin_amdgcn_mfma_f32_32x32x16_f16(wh, Bl[g], t, 0, 0, 0);
            }
#pragma unroll
            for (int i = 0; i < 16; ++i) aA[i] += aB[i];
            transition_ft(aA, ft, Ch, Cl);
        }

        // ---- L2: per-ft chain, dual acc; C -> B; 2 products ----
#pragma unroll
        for (int ft = 0; ft < 4; ++ft) {
            f32x16 aA, aB;
#pragma unroll
            for (int q4 = 0; q4 < 4; ++q4) {
                f32x4 t = *(const f32x4*)(smem + OFF_B2 + (ft * 32 + 4 * h + 8 * q4) * 4);
#pragma unroll
                for (int i = 0; i < 4; ++i) { aA[4 * q4 + i] = t[i]; aB[4 * q4 + i] = 0.f; }
            }
#pragma unroll
            for (int g = 0; g < 8; ++g) {
                f32x16& t = (g & 1) ? aB : aA;
                f16x8 wh = *(const f16x8*)(W2h + (ft * 8 + g) * 1024);
                t = __builtin_amdgcn_mfma_f32_32x32x16_f16(wh, Ch[g], t, 0, 0, 0);
                t = __builtin_amdgcn_mfma_f32_32x32x16_f16(wh, Cl[g], t, 0, 0, 0);
            }
#pragma unroll
            for (int i = 0; i < 16; ++i) aA[i] += aB[i];
            transition_ft(aA, ft, Bh, Bl);
        }

        // ---- out layer: WO streamed from L2, 3 products, dual acc ----
        f32x16 aA = {}, aB = {};
        aA[0] = h ? bo[4] : bo[0];
        aA[1] = h ? bo[5] : bo[1];
        aA[2] = h ? 0.f   : bo[2];
        aA[3] = h ? 0.f   : bo[3];
#pragma unroll
        for (int g = 0; g < 8; ++g) {
            f32x16& t = (g & 1) ? aB : aA;
            f16x8 wh = *(const f16x8*)(WOh + g * 1024);
            f16x8 wl = *(const f16x8*)(WOl + g * 1024);
            t = __builtin_amdgcn_mfma_f32_32x32x16_f16(wh, Bh[g], t, 0, 0, 0);
            t = __builtin_amdgcn_mfma_f32_32x32x16_f16(wh, Bl[g], t, 0, 0, 0);
            t = __builtin_amdgcn_mfma_f32_32x32x16_f16(wl, Bh[g], t, 0, 0, 0);
        }
        const int pt = pbase + c;
        if (h == 0) {
            *(float2*)(sws + pt * 6)     = make_float2(aA[0] + aB[0], aA[1] + aB[1]);
            *(float2*)(sws + pt * 6 + 2) = make_float2(aA[2] + aB[2], aA[3] + aB[3]);
        } else {
            *(float2*)(sws + pt * 6 + 4) = make_float2(aA[0] + aB[0], aA[1] + aB[1]);
        }
    }
}

// ===========================================================================
// K3: repair + deformation, literal f32 Rodrigues. grid 2048 x 128.
// ===========================================================================
__launch_bounds__(128)
__global__ void deform_kernel(const float* __restrict__ x,  const float* __restrict__ w0,
                              const float* __restrict__ w1, const float* __restrict__ b1,
                              const float* __restrict__ w2, const float* __restrict__ b2,
                              const float* __restrict__ wout, const float* __restrict__ bout,
                              const int* __restrict__ dsp, const float* __restrict__ vws,
                              float* __restrict__ sws, float* __restrict__ out,
                              float* __restrict__ partws) {
    __shared__ float sh_emb[96];
    __shared__ float sh_h[2][128];
    __shared__ int   sh_flag[128];
    __shared__ float sh_red[8];
    const int tid = threadIdx.x;
    const int r   = blockIdx.x;
    const int pt  = r * 128 + tid;

    float xv0 = x[pt * 3 + 0], xv1 = x[pt * 3 + 1], xv2 = x[pt * 3 + 2];
    float s6[6];
#pragma unroll
    for (int j = 0; j < 6; ++j) s6[j] = sws[pt * 6 + j];
    float q2 = s6[0] * s6[0] + s6[1] * s6[1] + s6[2] * s6[2];
    float xx = xv0 * xv0 + xv1 * xv1 + xv2 * xv2;
    float tt = s6[3] * s6[3] + s6[4] * s6[4] + s6[5] * s6[5];
    sh_flag[tid] = (q2 < KAPPA2_X2 * (xx + tt)) ? 1 : 0;
    __syncthreads();

    for (int pf = 0; pf < 128; ++pf) {
        if (!sh_flag[pf]) continue;
        int gpt = r * 128 + pf;
        if (tid < 96) {
            int   k2  = tid / 6, rem = tid - k2 * 6;
            int   dim = (rem >= 3) ? rem - 3 : rem;
            bool  isc = rem >= 3;
            float fr  = (float)(1 << k2);
            float cl  = fminf(fmaxf(read_ds(dsp) - (float)k2, 0.f), 1.f);
            float wk  = 0.5f * (1.f - cosf(PI_F * cl)) * expf(-0.5f * fr * fr * IPE_VAR);
            float ang = x[gpt * 3 + dim] * fr;
            double da = (double)ang;
            sh_emb[tid] = (float)(isc ? cos(da) : sin(da)) * wk;
        }
        __syncthreads();
        float acc = vws[r * 128 + tid];
#pragma unroll 8
        for (int f = 0; f < 96; ++f) acc += sh_emb[f] * w0[f * 128 + tid];
        sh_h[0][tid] = fmaxf(acc, 0.f);
        __syncthreads();
        acc = b1[tid];
#pragma unroll 8
        for (int cc = 0; cc < 128; ++cc) acc += sh_h[0][cc] * w1[cc * 128 + tid];
        sh_h[1][tid] = fmaxf(acc, 0.f);
        __syncthreads();
        acc = b2[tid];
#pragma unroll 8
        for (int cc = 0; cc < 128; ++cc) acc += sh_h[1][cc] * w2[cc * 128 + tid];
        sh_h[0][tid] = fmaxf(acc, 0.f);
        __syncthreads();
        if (tid < 6) {
            float sv = bout[tid];
#pragma unroll 8
            for (int cc = 0; cc < 128; ++cc) sv += sh_h[0][cc] * wout[cc * 6 + tid];
            sws[gpt * 6 + tid] = sv;
        }
        __syncthreads();
    }
#pragma unroll
    for (int j = 0; j < 6; ++j) s6[j] = sws[pt * 6 + j];

    float e0, e1, e2, p0, p1, p2, th, q2b, trp;
    {
#pragma clang fp contract(off)
        q2b = s6[0] * s6[0];
        q2b = q2b + s6[1] * s6[1];
        q2b = q2b + s6[2] * s6[2];
        th  = sqrtf(q2b);
        float ux = s6[0] / th, uy = s6[1] / th, uz = s6[2] / th;
        float sin_t = (float)sin((double)th);
        float cos_t = (float)cos((double)th);
        float thsq = th * th;
        float c1 = sin_t / th;
        float c2 = (1.0f - cos_t) / thsq;
        float c3 = (th - sin_t) / (thsq * th);
        float udx = ux * xv0 + uy * xv1 + uz * xv2;
        e0 = (1.f - c2) * xv0 + c2 * ux * udx + c1 * (uy * xv2 - uz * xv1);
        e1 = (1.f - c2) * xv1 + c2 * uy * udx + c1 * (uz * xv0 - ux * xv2);
        e2 = (1.f - c2) * xv2 + c2 * uz * udx + c1 * (ux * xv1 - uy * xv0);
        float t0 = s6[3], t1 = s6[4], t2 = s6[5];
        float udt = ux * t0 + uy * t1 + uz * t2;
        p0 = (1.f - c3) * t0 + c3 * ux * udt + c2 * (uy * t2 - uz * t1);
        p1 = (1.f - c3) * t1 + c3 * uy * udt + c2 * (uz * t0 - ux * t2);
        p2 = (1.f - c3) * t2 + c3 * uz * udt + c2 * (ux * t1 - uy * t0);
        trp = t0 * t0 + t1 * t1 + t2 * t2;
    }
    out[pt * 3 + 0] = e0 + p0;
    out[pt * 3 + 1] = e1 + p1;
    out[pt * 3 + 2] = e2 + p2;

    float lsp = q2b + trp;
    float rqp = th;
    float trq = trp;
    for (int off = 32; off; off >>= 1) {
        lsp += __shfl_down(lsp, off);
        rqp += __shfl_down(rqp, off);
        trq += __shfl_down(trq, off);
    }
    if ((tid & 63) == 0) {
        int w = tid >> 6;
        sh_red[w * 3 + 0] = lsp; sh_red[w * 3 + 1] = rqp; sh_red[w * 3 + 2] = trq;
    }
    __syncthreads();
    if (tid == 0) {
        partws[r * 3 + 0] = sh_red[0] + sh_red[3];
        partws[r * 3 + 1] = sh_red[1] + sh_red[4];
        partws[r * 3 + 2] = sh_red[2] + sh_red[5];
    }
}

// ===========================================================================
// K4: final scalar reduction.
// ===========================================================================
__launch_bounds__(256)
__global__ void final_kernel(const float* __restrict__ partws, float* __restrict__ out) {
    __shared__ float sh[12];
    const int tid = threadIdx.x;
    float a0 = 0.f, a1 = 0.f, a2 = 0.f;
    for (int i = tid; i < 2048; i += 256) {
        a0 += partws[i * 3 + 0]; a1 += partws[i * 3 + 1]; a2 += partws[i * 3 + 2];
    }
    for (int off = 32; off; off >>= 1) {
        a0 += __shfl_down(a0, off); a1 += __shfl_down(a1, off); a2 += __shfl_down(a2, off);
    }
    if ((tid & 63) == 0) {
        int w = tid >> 6;
        sh[w * 3 + 0] = a0; sh[w * 3 + 1] = a1; sh[w * 3 + 2] = a2;
    }
    __syncthreads();
    if (tid == 0) {
        float S0 = sh[0] + sh[3] + sh[6] + sh[9];
        float S1 = sh[1] + sh[4] + sh[7] + sh[10];
        float S2 = sh[2] + sh[5] + sh[8] + sh[11];
        out[786432] = S0 / ((float)NPTS * 6.f);
        out[786433] = S1 * (180.f / PI_F) / (float)NPTS;
        out[786434] = S2 / ((float)NPTS * 3.f);
    }
}

// ===========================================================================
extern "C" void kernel_launch(void* const* d_in, const int* in_sizes, int n_in,
                              void* d_out, int out_size, void* d_ws, size_t ws_size,
                              hipStream_t stream) {
    const float* x     = (const float*)d_in[0];
    const float* dc    = (const float*)d_in[1];
    const float* wproj = (const float*)d_in[2];
    const float* bproj = (const float*)d_in[3];
    const float* w0    = (const float*)d_in[4];
    const float* b0    = (const float*)d_in[5];
    const float* w1    = (const float*)d_in[6];
    const float* b1    = (const float*)d_in[7];
    const float* w2    = (const float*)d_in[8];
    const float* b2    = (const float*)d_in[9];
    const float* wout  = (const float*)d_in[10];
    const float* bout  = (const float*)d_in[11];
    const int*   dsp   = (const int*)d_in[12];
    float* out = (float*)d_out;
    char*  ws  = (char*)d_ws;

    float* vws    = (float*)(ws + WSO_V);
    float* sws    = (float*)(ws + WSO_S);
    float* partws = (float*)(ws + WSO_PART);

    prep_kernel<<<256, 128, 0, stream>>>(dc, wproj, bproj, w0, b0, vws);
    lofill_kernel<<<21, 256, 0, stream>>>(w0, w1, w2, wout, ws);
    mlp_kernel<<<256, 512, 0, stream>>>(x, b1, b2, bout, dsp, vws, sws, ws);
    deform_kernel<<<2048, 128, 0, stream>>>(x, w0, w1, b1, w2, b2, wout, bout, dsp,
                                            vws, sws, out, partws);
    final_kernel<<<1, 256, 0, stream>>>(partws, out);
}

// Round 16
// 100.488 us; speedup vs baseline: 12.6606x; 12.6606x over previous
//
#include <hip/hip_runtime.h>

// ---------------------------------------------------------------------------
// Deformation MLP, MI355X (gfx950).  Round 16 = round 14 verbatim (revert of
// the r15 2-product experiment, which shifted cost into mass repair).
// W0/W1/W2 hi+lo ALL in LDS; W-out streamed per-tile from ws/L2.
// Serial per-ft chains + dual-acc ILP, 3-product Ootomo split,
// literal-f32 Rodrigues, tiny-theta repair (kappa^2 = 4e-9).
// Proven: total 100.7 us, mlp 76 us, zero spill (VGPR 124, WRITE = sws only).
// ---------------------------------------------------------------------------

typedef __fp16   fp16x2 __attribute__((ext_vector_type(2)));
typedef _Float16 f16x8  __attribute__((ext_vector_type(8)));
typedef float    f32x4  __attribute__((ext_vector_type(4)));
typedef float    f32x16 __attribute__((ext_vector_type(16)));
typedef unsigned u32x4  __attribute__((ext_vector_type(4)));

#define PI_F 3.14159265358979323846f
constexpr int   BATCH = 2048;
constexpr int   NPTS  = BATCH * 128;
constexpr float IPE_VAR = 1e-4f;
constexpr float KAPPA2_X2 = 4e-9f;   // repair if th^2 < this*(xx+tt)

// ---- ws layout (bytes) ----
constexpr int WSO_V    = 0;          // 1,048,576
constexpr int WSO_S    = 1048576;    // 6,291,456
constexpr int WSO_PART = 7340032;    // 24,576
constexpr int WSO_TAB  = 7364608;    // contiguous tables copied to LDS:
constexpr int TB_W0H = 0;            // 128x48  hi  : 12288
constexpr int TB_W1H = 12288;        // 128x128 hi  : 32768
constexpr int TB_W2H = 45056;        // 128x128 hi  : 32768
constexpr int TB_W0L = 77824;        // lo          : 12288
constexpr int TB_W1L = 90112;        // lo          : 32768
constexpr int TB_W2L = 122880;       // lo          : 32768
constexpr int TB_SZ  = 155648;       // 152 KB tables (all -> LDS)
constexpr int WSO_WOH = WSO_TAB + TB_SZ;          // 8192 (streamed from L2)
constexpr int WSO_WOL = WSO_TAB + TB_SZ + 8192;   // 8192 (streamed from L2)

// ---- extra LDS past the tables ----
constexpr int OFF_B1   = TB_SZ;            // 512
constexpr int OFF_B2   = TB_SZ + 512;      // 512
constexpr int OFF_VR   = TB_SZ + 1024;     // 8 rows x 128 f32 = 4096
constexpr int SMEM_TOT = TB_SZ + 1024 + 4096;   // 160,768 B (<= 163,840)

__device__ __forceinline__ float read_ds(const int* p) {
    int iv = p[0];
    if (iv >= 0 && iv <= 64) return (float)iv;
    return ((const float*)p)[0];
}

// exact hi/lo fp16 split of a float pair: hi = pkrtz(a,b); lo absorbs residual
__device__ __forceinline__ void split2(float a, float b, unsigned& hi, unsigned& lo) {
    fp16x2 h = __builtin_amdgcn_cvt_pkrtz(a, b);
    fp16x2 l = __builtin_amdgcn_cvt_pkrtz(a - (float)h[0], b - (float)h[1]);
    hi = __builtin_bit_cast(unsigned, h);
    lo = __builtin_bit_cast(unsigned, l);
}

// v_permlane32_swap_b32: a' = {a[0:31], b[0:31]}, b' = {a[32:63], b[32:63]}
__device__ __forceinline__ void permswap(unsigned& a, unsigned& b) {
    asm("v_permlane32_swap_b32 %0, %1" : "+v"(a), "+v"(b));
}

// ===========================================================================
// K1: per-batch prep. grid 256 x 128 threads, 8 batches per block.
// ===========================================================================
__launch_bounds__(128)
__global__ void prep_kernel(const float* __restrict__ dc, const float* __restrict__ wproj,
                            const float* __restrict__ bproj, const float* __restrict__ w0,
                            const float* __restrict__ b0, float* __restrict__ vws) {
    __shared__ float dcn[8][128];
    __shared__ float dcp[8][128];
    __shared__ float red[2];
    const int tid = threadIdx.x;
    const int bb  = blockIdx.x * 8;

    for (int bi = 0; bi < 8; ++bi) {
        float val = dc[(bb + bi) * 128 + tid];
        float sq  = val * val;
        for (int off = 32; off; off >>= 1) sq += __shfl_down(sq, off);
        if ((tid & 63) == 0) red[tid >> 6] = sq;
        __syncthreads();
        float nrm = sqrtf(red[0] + red[1]);
        dcn[bi][tid] = val / fmaxf(nrm, 1e-12f);
        __syncthreads();
    }
    float acc[8];
#pragma unroll
    for (int bi = 0; bi < 8; ++bi) acc[bi] = bproj[tid];
    for (int c = 0; c < 128; ++c) {
        float w = wproj[c * 128 + tid];
#pragma unroll
        for (int bi = 0; bi < 8; ++bi) acc[bi] += dcn[bi][c] * w;
    }
#pragma unroll
    for (int bi = 0; bi < 8; ++bi) dcp[bi][tid] = acc[bi];
    __syncthreads();
#pragma unroll
    for (int bi = 0; bi < 8; ++bi) acc[bi] = b0[tid];
    for (int c = 0; c < 128; ++c) {
        float w = w0[(96 + c) * 128 + tid];
#pragma unroll
        for (int bi = 0; bi < 8; ++bi) acc[bi] += dcp[bi][c] * w;
    }
#pragma unroll
    for (int bi = 0; bi < 8; ++bi) vws[(bb + bi) * 128 + tid] = acc[bi];
}

// ===========================================================================
// K1b: build fragment-linear (32x32x16 form) hi+lo fp16 weight tables in ws.
// ===========================================================================
__launch_bounds__(256)
__global__ void lofill_kernel(const float* __restrict__ w0, const float* __restrict__ w1,
                              const float* __restrict__ w2, const float* __restrict__ wout,
                              char* __restrict__ ws) {
    int i = blockIdx.x * 256 + threadIdx.x;
    if (i >= 5376) return;
    float src[8];
    int dstH, dstL;
    if (i < 768) {                          // W0: 128 n x 6 kb (K=48, G=3)
        int n = i & 127, kb = i >> 7;
#pragma unroll
        for (int j = 0; j < 8; ++j) src[j] = w0[(kb * 8 + j) * 128 + n];
        int off = ((n >> 5) * 3 + (kb >> 1)) * 1024 + (((n & 31) | ((kb & 1) << 5)) << 4);
        dstH = WSO_TAB + TB_W0H + off;  dstL = WSO_TAB + TB_W0L + off;
    } else if (i < 768 + 2048) {            // W1: 128 x 16 kb (G=8)
        int t = i - 768; int n = t & 127, kb = t >> 7;
#pragma unroll
        for (int j = 0; j < 8; ++j) src[j] = w1[(kb * 8 + j) * 128 + n];
        int off = ((n >> 5) * 8 + (kb >> 1)) * 1024 + (((n & 31) | ((kb & 1) << 5)) << 4);
        dstH = WSO_TAB + TB_W1H + off;  dstL = WSO_TAB + TB_W1L + off;
    } else if (i < 768 + 4096) {            // W2: hi AND lo -> LDS tables
        int t = i - 768 - 2048; int n = t & 127, kb = t >> 7;
#pragma unroll
        for (int j = 0; j < 8; ++j) src[j] = w2[(kb * 8 + j) * 128 + n];
        int off = ((n >> 5) * 8 + (kb >> 1)) * 1024 + (((n & 31) | ((kb & 1) << 5)) << 4);
        dstH = WSO_TAB + TB_W2H + off;  dstL = WSO_TAB + TB_W2L + off;
    } else {                                // WO: 32 idx (6 real) x 16 kb (G=8)
        int t = i - 768 - 4096; int idx = t & 31, kb = t >> 5;
#pragma unroll
        for (int j = 0; j < 8; ++j) {
            int k = kb * 8 + j;
            src[j] = (idx < 6) ? wout[k * 6 + idx] : 0.f;
        }
        int off = (kb >> 1) * 1024 + (((idx & 31) | ((kb & 1) << 5)) << 4);
        dstH = WSO_WOH + off;  dstL = WSO_WOL + off;
    }
    f16x8 vh, vl;
#pragma unroll
    for (int j = 0; j < 8; ++j) {
        _Float16 h = (_Float16)src[j];
        vh[j] = h;
        vl[j] = (_Float16)(src[j] - (float)h);
    }
    *(f16x8*)(ws + dstH) = vh;
    *(f16x8*)(ws + dstL) = vl;
}

// ===========================================================================
// K2: fused MLP, barrier-free, per-ft serial chains + dual-acc ILP.
// W0/W1/W2 in LDS; WO streamed from L2. grid 256 x 512 (8 waves).
// ===========================================================================
__device__ __forceinline__ void transition_ft(const f32x16& acc, int ft,
                                              f16x8 (&Bh)[8], f16x8 (&Bl)[8]) {
    unsigned hp[8], lp[8];
#pragma unroll
    for (int r2 = 0; r2 < 8; ++r2) {
        float f0 = fmaxf(acc[2 * r2],     0.f);
        float f1 = fmaxf(acc[2 * r2 + 1], 0.f);
        split2(f0, f1, hp[r2], lp[r2]);
    }
#pragma unroll
    for (int gg = 0; gg < 2; ++gg) {
        int g = 2 * ft + gg, P = 4 * gg;
        unsigned a = hp[P], b = hp[P + 1], c = hp[P + 2], d = hp[P + 3];
        permswap(a, c); permswap(b, d);
        Bh[g] = __builtin_bit_cast(f16x8, (u32x4){a, b, c, d});
        a = lp[P]; b = lp[P + 1]; c = lp[P + 2]; d = lp[P + 3];
        permswap(a, c); permswap(b, d);
        Bl[g] = __builtin_bit_cast(f16x8, (u32x4){a, b, c, d});
    }
}

__global__ void __launch_bounds__(512, 2)
mlp_kernel(const float* __restrict__ x,  const float* __restrict__ b1,
           const float* __restrict__ b2, const float* __restrict__ bout,
           const int* __restrict__ dsp,  const float* __restrict__ vws,
           float* __restrict__ sws,      const char* __restrict__ ws) {
    alignas(16) __shared__ char smem[SMEM_TOT];
    const int tid  = threadIdx.x;
    const int lane = tid & 63;
    const int wv   = tid >> 6;
    const int h    = lane >> 5;      // lane half
    const int c    = lane & 31;      // point-within-32 / col

    // ---- stage tables + biases + vws rows -> LDS, single barrier ----
    {
        const u32x4* src = (const u32x4*)(ws + WSO_TAB);
        u32x4* dst = (u32x4*)smem;
        for (int i = tid; i < TB_SZ / 16; i += 512) dst[i] = src[i];
        if (tid < 128)      ((float*)(smem + OFF_B1))[tid]       = b1[tid];
        else if (tid < 256) ((float*)(smem + OFF_B2))[tid - 128] = b2[tid - 128];
        float* vr = (float*)(smem + OFF_VR);
        for (int i = tid; i < 1024; i += 512) vr[i] = vws[blockIdx.x * 1024 + i];
    }
    __syncthreads();

    const int laneoff = lane << 4;
    const char* W0h = smem + TB_W0H + laneoff;
    const char* W1h = smem + TB_W1H + laneoff;
    const char* W2h = smem + TB_W2H + laneoff;
    const char* W0l = smem + TB_W0L + laneoff;
    const char* W1l = smem + TB_W1L + laneoff;
    const char* W2l = smem + TB_W2L + laneoff;
    const char* WOh = ws + WSO_WOH + laneoff;   // streamed from L1/L2
    const char* WOl = ws + WSO_WOL + laneoff;

    float win[8];
    {
        float dsv = read_ds(dsp);
#pragma unroll
        for (int k2 = 0; k2 < 8; ++k2) {
            float fr = (float)(1 << k2);
            float cl = fminf(fmaxf(dsv - (float)k2, 0.f), 1.f);
            win[k2] = 0.5f * (1.f - cosf(PI_F * cl)) * expf(-0.5f * fr * fr * IPE_VAR);
        }
    }
    float bo[6];
#pragma unroll
    for (int i = 0; i < 6; ++i) bo[i] = bout[i];

    const int tbase = blockIdx.x * 32 + wv * 4;
    const int vroff = wv * 128;                 // this wave's v-row in LDS

#pragma unroll 1
    for (int it = 0; it < 4; ++it) {
        const int tile  = tbase + it;
        const int pbase = tile * 32;

        // ---- fourier embedding -> B0 frags (K=48, 3 k-slices) ----
        f16x8 B0h[3], B0l[3];
        {
            float vals[48];
            float sv[3], cv[3];
#pragma unroll
            for (int d = 0; d < 3; ++d) {
                float xv = x[(pbase + c) * 3 + d];
                sv[d] = sinf(xv); cv[d] = cosf(xv);
            }
#pragma unroll
            for (int k2 = 0; k2 < 8; ++k2) {
#pragma unroll
                for (int d = 0; d < 3; ++d) {
                    vals[6 * k2 + d]     = sv[d] * win[k2];
                    vals[6 * k2 + 3 + d] = cv[d] * win[k2];
                }
#pragma unroll
                for (int d = 0; d < 3; ++d) {
                    float ns = 2.f * sv[d] * cv[d];
                    cv[d] = 1.f - 2.f * sv[d] * sv[d];
                    sv[d] = ns;
                }
            }
#pragma unroll
            for (int g = 0; g < 3; ++g) {
                u32x4 wh_, wl_;
#pragma unroll
                for (int w = 0; w < 4; ++w) {
                    float va = h ? vals[16 * g + 8 + 2 * w]     : vals[16 * g + 2 * w];
                    float vb = h ? vals[16 * g + 8 + 2 * w + 1] : vals[16 * g + 2 * w + 1];
                    unsigned uh, ul;
                    split2(va, vb, uh, ul);
                    wh_[w] = uh; wl_[w] = ul;
                }
                B0h[g] = __builtin_bit_cast(f16x8, wh_);
                B0l[g] = __builtin_bit_cast(f16x8, wl_);
            }
        }

        // ---- L0: per-ft chain, dual acc (even g -> aA, odd g -> aB) ----
        f16x8 Bh[8], Bl[8];
#pragma unroll
        for (int ft = 0; ft < 4; ++ft) {
            f32x16 aA, aB;
#pragma unroll
            for (int q4 = 0; q4 < 4; ++q4) {
                f32x4 t = *(const f32x4*)(smem + OFF_VR + (vroff + ft * 32 + 4 * h + 8 * q4) * 4);
#pragma unroll
                for (int i = 0; i < 4; ++i) { aA[4 * q4 + i] = t[i]; aB[4 * q4 + i] = 0.f; }
            }
#pragma unroll
            for (int g = 0; g < 3; ++g) {
                f32x16& t = (g & 1) ? aB : aA;
                f16x8 wh = *(const f16x8*)(W0h + (ft * 3 + g) * 1024);
                t = __builtin_amdgcn_mfma_f32_32x32x16_f16(wh, B0h[g], t, 0, 0, 0);
                t = __builtin_amdgcn_mfma_f32_32x32x16_f16(wh, B0l[g], t, 0, 0, 0);
                f16x8 wl = *(const f16x8*)(W0l + (ft * 3 + g) * 1024);
                t = __builtin_amdgcn_mfma_f32_32x32x16_f16(wl, B0h[g], t, 0, 0, 0);
            }
#pragma unroll
            for (int i = 0; i < 16; ++i) aA[i] += aB[i];
            transition_ft(aA, ft, Bh, Bl);
        }

        // ---- L1: per-ft chain, dual acc; B -> C ----
        f16x8 Ch[8], Cl[8];
#pragma unroll
        for (int ft = 0; ft < 4; ++ft) {
            f32x16 aA, aB;
#pragma unroll
            for (int q4 = 0; q4 < 4; ++q4) {
                f32x4 t = *(const f32x4*)(smem + OFF_B1 + (ft * 32 + 4 * h + 8 * q4) * 4);
#pragma unroll
                for (int i = 0; i < 4; ++i) { aA[4 * q4 + i] = t[i]; aB[4 * q4 + i] = 0.f; }
            }
#pragma unroll
            for (int g = 0; g < 8; ++g) {
                f32x16& t = (g & 1) ? aB : aA;
                f16x8 wh = *(const f16x8*)(W1h + (ft * 8 + g) * 1024);
                t = __builtin_amdgcn_mfma_f32_32x32x16_f16(wh, Bh[g], t, 0, 0, 0);
                t = __builtin_amdgcn_mfma_f32_32x32x16_f16(wh, Bl[g], t, 0, 0, 0);
                f16x8 wl = *(const f16x8*)(W1l + (ft * 8 + g) * 1024);
                t = __builtin_amdgcn_mfma_f32_32x32x16_f16(wl, Bh[g], t, 0, 0, 0);
            }
#pragma unroll
            for (int i = 0; i < 16; ++i) aA[i] += aB[i];
            transition_ft(aA, ft, Ch, Cl);
        }

        // ---- L2: per-ft chain, dual acc; C -> B; all LDS ----
#pragma unroll
        for (int ft = 0; ft < 4; ++ft) {
            f32x16 aA, aB;
#pragma unroll
            for (int q4 = 0; q4 < 4; ++q4) {
                f32x4 t = *(const f32x4*)(smem + OFF_B2 + (ft * 32 + 4 * h + 8 * q4) * 4);
#pragma unroll
                for (int i = 0; i < 4; ++i) { aA[4 * q4 + i] = t[i]; aB[4 * q4 + i] = 0.f; }
            }
#pragma unroll
            for (int g = 0; g < 8; ++g) {
                f32x16& t = (g & 1) ? aB : aA;
                f16x8 wh = *(const f16x8*)(W2h + (ft * 8 + g) * 1024);
                t = __builtin_amdgcn_mfma_f32_32x32x16_f16(wh, Ch[g], t, 0, 0, 0);
                t = __builtin_amdgcn_mfma_f32_32x32x16_f16(wh, Cl[g], t, 0, 0, 0);
                f16x8 wl = *(const f16x8*)(W2l + (ft * 8 + g) * 1024);
                t = __builtin_amdgcn_mfma_f32_32x32x16_f16(wl, Ch[g], t, 0, 0, 0);
            }
#pragma unroll
            for (int i = 0; i < 16; ++i) aA[i] += aB[i];
            transition_ft(aA, ft, Bh, Bl);
        }

        // ---- out layer: WO streamed from L2, dual acc ----
        f32x16 aA = {}, aB = {};
        aA[0] = h ? bo[4] : bo[0];
        aA[1] = h ? bo[5] : bo[1];
        aA[2] = h ? 0.f   : bo[2];
        aA[3] = h ? 0.f   : bo[3];
#pragma unroll
        for (int g = 0; g < 8; ++g) {
            f32x16& t = (g & 1) ? aB : aA;
            f16x8 wh = *(const f16x8*)(WOh + g * 1024);
            f16x8 wl = *(const f16x8*)(WOl + g * 1024);
            t = __builtin_amdgcn_mfma_f32_32x32x16_f16(wh, Bh[g], t, 0, 0, 0);
            t = __builtin_amdgcn_mfma_f32_32x32x16_f16(wh, Bl[g], t, 0, 0, 0);
            t = __builtin_amdgcn_mfma_f32_32x32x16_f16(wl, Bh[g], t, 0, 0, 0);
        }
        const int pt = pbase + c;
        if (h == 0) {
            *(float2*)(sws + pt * 6)     = make_float2(aA[0] + aB[0], aA[1] + aB[1]);
            *(float2*)(sws + pt * 6 + 2) = make_float2(aA[2] + aB[2], aA[3] + aB[3]);
        } else {
            *(float2*)(sws + pt * 6 + 4) = make_float2(aA[0] + aB[0], aA[1] + aB[1]);
        }
    }
}

// ===========================================================================
// K3: repair + deformation, literal f32 Rodrigues. grid 2048 x 128.
// ===========================================================================
__launch_bounds__(128)
__global__ void deform_kernel(const float* __restrict__ x,  const float* __restrict__ w0,
                              const float* __restrict__ w1, const float* __restrict__ b1,
                              const float* __restrict__ w2, const float* __restrict__ b2,
                              const float* __restrict__ wout, const float* __restrict__ bout,
                              const int* __restrict__ dsp, const float* __restrict__ vws,
                              float* __restrict__ sws, float* __restrict__ out,
                              float* __restrict__ partws) {
    __shared__ float sh_emb[96];
    __shared__ float sh_h[2][128];
    __shared__ int   sh_flag[128];
    __shared__ float sh_red[8];
    const int tid = threadIdx.x;
    const int r   = blockIdx.x;
    const int pt  = r * 128 + tid;

    float xv0 = x[pt * 3 + 0], xv1 = x[pt * 3 + 1], xv2 = x[pt * 3 + 2];
    float s6[6];
#pragma unroll
    for (int j = 0; j < 6; ++j) s6[j] = sws[pt * 6 + j];
    float q2 = s6[0] * s6[0] + s6[1] * s6[1] + s6[2] * s6[2];
    float xx = xv0 * xv0 + xv1 * xv1 + xv2 * xv2;
    float tt = s6[3] * s6[3] + s6[4] * s6[4] + s6[5] * s6[5];
    sh_flag[tid] = (q2 < KAPPA2_X2 * (xx + tt)) ? 1 : 0;
    __syncthreads();

    for (int pf = 0; pf < 128; ++pf) {
        if (!sh_flag[pf]) continue;
        int gpt = r * 128 + pf;
        if (tid < 96) {
            int   k2  = tid / 6, rem = tid - k2 * 6;
            int   dim = (rem >= 3) ? rem - 3 : rem;
            bool  isc = rem >= 3;
            float fr  = (float)(1 << k2);
            float cl  = fminf(fmaxf(read_ds(dsp) - (float)k2, 0.f), 1.f);
            float wk  = 0.5f * (1.f - cosf(PI_F * cl)) * expf(-0.5f * fr * fr * IPE_VAR);
            float ang = x[gpt * 3 + dim] * fr;
            double da = (double)ang;
            sh_emb[tid] = (float)(isc ? cos(da) : sin(da)) * wk;
        }
        __syncthreads();
        float acc = vws[r * 128 + tid];
#pragma unroll 8
        for (int f = 0; f < 96; ++f) acc += sh_emb[f] * w0[f * 128 + tid];
        sh_h[0][tid] = fmaxf(acc, 0.f);
        __syncthreads();
        acc = b1[tid];
#pragma unroll 8
        for (int cc = 0; cc < 128; ++cc) acc += sh_h[0][cc] * w1[cc * 128 + tid];
        sh_h[1][tid] = fmaxf(acc, 0.f);
        __syncthreads();
        acc = b2[tid];
#pragma unroll 8
        for (int cc = 0; cc < 128; ++cc) acc += sh_h[1][cc] * w2[cc * 128 + tid];
        sh_h[0][tid] = fmaxf(acc, 0.f);
        __syncthreads();
        if (tid < 6) {
            float sv = bout[tid];
#pragma unroll 8
            for (int cc = 0; cc < 128; ++cc) sv += sh_h[0][cc] * wout[cc * 6 + tid];
            sws[gpt * 6 + tid] = sv;
        }
        __syncthreads();
    }
#pragma unroll
    for (int j = 0; j < 6; ++j) s6[j] = sws[pt * 6 + j];

    float e0, e1, e2, p0, p1, p2, th, q2b, trp;
    {
#pragma clang fp contract(off)
        q2b = s6[0] * s6[0];
        q2b = q2b + s6[1] * s6[1];
        q2b = q2b + s6[2] * s6[2];
        th  = sqrtf(q2b);
        float ux = s6[0] / th, uy = s6[1] / th, uz = s6[2] / th;
        float sin_t = (float)sin((double)th);
        float cos_t = (float)cos((double)th);
        float thsq = th * th;
        float c1 = sin_t / th;
        float c2 = (1.0f - cos_t) / thsq;
        float c3 = (th - sin_t) / (thsq * th);
        float udx = ux * xv0 + uy * xv1 + uz * xv2;
        e0 = (1.f - c2) * xv0 + c2 * ux * udx + c1 * (uy * xv2 - uz * xv1);
        e1 = (1.f - c2) * xv1 + c2 * uy * udx + c1 * (uz * xv0 - ux * xv2);
        e2 = (1.f - c2) * xv2 + c2 * uz * udx + c1 * (ux * xv1 - uy * xv0);
        float t0 = s6[3], t1 = s6[4], t2 = s6[5];
        float udt = ux * t0 + uy * t1 + uz * t2;
        p0 = (1.f - c3) * t0 + c3 * ux * udt + c2 * (uy * t2 - uz * t1);
        p1 = (1.f - c3) * t1 + c3 * uy * udt + c2 * (uz * t0 - ux * t2);
        p2 = (1.f - c3) * t2 + c3 * uz * udt + c2 * (ux * t1 - uy * t0);
        trp = t0 * t0 + t1 * t1 + t2 * t2;
    }
    out[pt * 3 + 0] = e0 + p0;
    out[pt * 3 + 1] = e1 + p1;
    out[pt * 3 + 2] = e2 + p2;

    float lsp = q2b + trp;
    float rqp = th;
    float trq = trp;
    for (int off = 32; off; off >>= 1) {
        lsp += __shfl_down(lsp, off);
        rqp += __shfl_down(rqp, off);
        trq += __shfl_down(trq, off);
    }
    if ((tid & 63) == 0) {
        int w = tid >> 6;
        sh_red[w * 3 + 0] = lsp; sh_red[w * 3 + 1] = rqp; sh_red[w * 3 + 2] = trq;
    }
    __syncthreads();
    if (tid == 0) {
        partws[r * 3 + 0] = sh_red[0] + sh_red[3];
        partws[r * 3 + 1] = sh_red[1] + sh_red[4];
        partws[r * 3 + 2] = sh_red[2] + sh_red[5];
    }
}

// ===========================================================================
// K4: final scalar reduction.
// ===========================================================================
__launch_bounds__(256)
__global__ void final_kernel(const float* __restrict__ partws, float* __restrict__ out) {
    __shared__ float sh[12];
    const int tid = threadIdx.x;
    float a0 = 0.f, a1 = 0.f, a2 = 0.f;
    for (int i = tid; i < 2048; i += 256) {
        a0 += partws[i * 3 + 0]; a1 += partws[i * 3 + 1]; a2 += partws[i * 3 + 2];
    }
    for (int off = 32; off; off >>= 1) {
        a0 += __shfl_down(a0, off); a1 += __shfl_down(a1, off); a2 += __shfl_down(a2, off);
    }
    if ((tid & 63) == 0) {
        int w = tid >> 6;
        sh[w * 3 + 0] = a0; sh[w * 3 + 1] = a1; sh[w * 3 + 2] = a2;
    }
    __syncthreads();
    if (tid == 0) {
        float S0 = sh[0] + sh[3] + sh[6] + sh[9];
        float S1 = sh[1] + sh[4] + sh[7] + sh[10];
        float S2 = sh[2] + sh[5] + sh[8] + sh[11];
        out[786432] = S0 / ((float)NPTS * 6.f);
        out[786433] = S1 * (180.f / PI_F) / (float)NPTS;
        out[786434] = S2 / ((float)NPTS * 3.f);
    }
}

// ===========================================================================
extern "C" void kernel_launch(void* const* d_in, const int* in_sizes, int n_in,
                              void* d_out, int out_size, void* d_ws, size_t ws_size,
                              hipStream_t stream) {
    const float* x     = (const float*)d_in[0];
    const float* dc    = (const float*)d_in[1];
    const float* wproj = (const float*)d_in[2];
    const float* bproj = (const float*)d_in[3];
    const float* w0    = (const float*)d_in[4];
    const float* b0    = (const float*)d_in[5];
    const float* w1    = (const float*)d_in[6];
    const float* b1    = (const float*)d_in[7];
    const float* w2    = (const float*)d_in[8];
    const float* b2    = (const float*)d_in[9];
    const float* wout  = (const float*)d_in[10];
    const float* bout  = (const float*)d_in[11];
    const int*   dsp   = (const int*)d_in[12];
    float* out = (float*)d_out;
    char*  ws  = (char*)d_ws;

    float* vws    = (float*)(ws + WSO_V);
    float* sws    = (float*)(ws + WSO_S);
    float* partws = (float*)(ws + WSO_PART);

    prep_kernel<<<256, 128, 0, stream>>>(dc, wproj, bproj, w0, b0, vws);
    lofill_kernel<<<21, 256, 0, stream>>>(w0, w1, w2, wout, ws);
    mlp_kernel<<<256, 512, 0, stream>>>(x, b1, b2, bout, dsp, vws, sws, ws);
    deform_kernel<<<2048, 128, 0, stream>>>(x, w0, w1, b1, w2, b2, wout, bout, dsp,
                                            vws, sws, out, partws);
    final_kernel<<<1, 256, 0, stream>>>(partws, out);
}